// Round 1
// baseline (312.229 us; speedup 1.0000x reference)
//
#include <hip/hip_runtime.h>
#include <stdint.h>

#define R 128
#define NB 64

// workspace float offsets
#define CAM0_OFF 0          // 64*128*784 = 6422528
#define CAM1_OFF 6422528    // 64*128*196 = 1605632
#define CAM2_OFF 8028160    // 64*128*49  = 401408
#define POOL0_OFF 8429568   // 1605632
#define POOL1_OFF 10035200  // 401408
#define WB_OFF    10436608  // 458752 bf16 = 229376 float slots
#define PART_OFF  10665984  // 2*64*16384 = 2097152
// total 12763136 floats ~= 48.7 MB

typedef __bf16 bf16;
typedef bf16 v8bf __attribute__((ext_vector_type(8)));
typedef float f4v __attribute__((ext_vector_type(4)));

// ---------------- prep: w fp32 -> bf16 (row-major, levels concatenated) -----
__global__ void prep_w(const float* __restrict__ w0, const float* __restrict__ w1,
                       const float* __restrict__ w2, bf16* __restrict__ wb) {
    int id = blockIdx.x * 256 + threadIdx.x;   // < 458752 exact
    float v;
    if (id < 65536)       v = w0[id];
    else if (id < 196608) v = w1[id - 65536];
    else                  v = w2[id - 196608];
    wb[id] = (bf16)v;
}

// ---------------- cam GEMM: cam[b,r,i] = sum_c w[r,c]*fmap[b,c,i] ----------
// flat N = b*HW + i ; BM=128, BN=64, BK=64 ; 4 waves as 2x2 (wave tile 64x32)
__global__ __launch_bounds__(256) void cam_gemm(
    const float* __restrict__ f0, const float* __restrict__ f1,
    const float* __restrict__ f2, const bf16* __restrict__ wb,
    float* __restrict__ ws) {
    __shared__ bf16  ldsA[128 * 72];   // [m][k] pad 64->72 (2-way free)
    __shared__ float ldsB[64 * 64];    // [k][n] fp32, 16B-chunk rotated

    int bid = blockIdx.x, tid = threadIdx.x;
    int lvl, tile;
    if (bid < 49)       { lvl = 2; tile = bid; }        // l2 first (heaviest blocks)
    else if (bid < 245) { lvl = 1; tile = bid - 49; }
    else                { lvl = 0; tile = bid - 245; }
    const int C  = (lvl == 0) ? 512 : (lvl == 1) ? 1024 : 2048;
    const int HW = (lvl == 0) ? 784 : (lvl == 1) ? 196  : 49;
    const float* fmap = (lvl == 0) ? f0 : (lvl == 1) ? f1 : f2;
    const bf16*  wbl  = wb + ((lvl == 0) ? 0 : (lvl == 1) ? 65536 : 196608);
    float* cam = ws + ((lvl == 0) ? CAM0_OFF : (lvl == 1) ? CAM1_OFF : CAM2_OFF);
    const int n0 = tile * 64;

    // B-staging per-lane precompute: 4 passes, each a 16B chunk (4 elems, b-crossing safe)
    int boff[4][4];
    int bldsoff[4];
#pragma unroll
    for (int pass = 0; pass < 4; ++pass) {
        int ch = pass * 256 + tid;        // 0..1023
        int k = ch >> 4, c = ch & 15;
        int p = (c + ((k >> 3) & 3) * 4) & 15;   // rotation swizzle
        bldsoff[pass] = k * 64 + p * 4;          // float index
#pragma unroll
        for (int e = 0; e < 4; ++e) {
            int n = n0 + c * 4 + e;
            int b = n / HW, i = n - b * HW;
            boff[pass][e] = b * C * HW + i + k * HW;
        }
    }
    const int lane = tid & 63, wave = tid >> 6;
    const int lm = lane & 15, q = lane >> 4;
    const int wm = (wave >> 1) * 64, wn = (wave & 1) * 32;
    int bIdx[2], bv[2], iv[2];
#pragma unroll
    for (int sn = 0; sn < 2; ++sn) {
        int nl = wn + sn * 16 + lm;
        int P = ((nl >> 2) + 4 * q) & 15;        // matches staging rotation (k>>3)&3 == q
        bIdx[sn] = P * 4 + (nl & 3);
        int n = n0 + nl;
        bv[sn] = n / HW; iv[sn] = n - bv[sn] * HW;
    }

    f4v acc[4][2] = {};
    for (int kc = 0; kc < C; kc += 64) {
        // stage A (bf16 copy)
#pragma unroll
        for (int pass = 0; pass < 4; ++pass) {
            int ch = pass * 256 + tid;
            int r = ch >> 3, ko = (ch & 7) * 8;
            *(int4*)&ldsA[r * 72 + ko] = *(const int4*)&wbl[r * C + kc + ko];
        }
        // stage B (fp32, per-element gather -> packed b128 write)
        int kb = kc * HW;
#pragma unroll
        for (int pass = 0; pass < 4; ++pass) {
            float4 v;
            v.x = fmap[boff[pass][0] + kb];
            v.y = fmap[boff[pass][1] + kb];
            v.z = fmap[boff[pass][2] + kb];
            v.w = fmap[boff[pass][3] + kb];
            *(float4*)&ldsB[bldsoff[pass]] = v;
        }
        __syncthreads();
#pragma unroll
        for (int ks = 0; ks < 64; ks += 32) {
            v8bf af[4];
#pragma unroll
            for (int sm = 0; sm < 4; ++sm)
                af[sm] = *(const v8bf*)&ldsA[(wm + sm * 16 + lm) * 72 + ks + q * 8];
            v8bf bfr[2];
#pragma unroll
            for (int sn = 0; sn < 2; ++sn) {
#pragma unroll
                for (int j = 0; j < 8; ++j)
                    bfr[sn][j] = (bf16)ldsB[(ks + q * 8 + j) * 64 + bIdx[sn]];
            }
#pragma unroll
            for (int sm = 0; sm < 4; ++sm)
#pragma unroll
                for (int sn = 0; sn < 2; ++sn)
                    acc[sm][sn] = __builtin_amdgcn_mfma_f32_16x16x32_bf16(
                        af[sm], bfr[sn], acc[sm][sn], 0, 0, 0);
        }
        __syncthreads();
    }
    // epilogue: D row = q*4+reg, col = lm
#pragma unroll
    for (int sn = 0; sn < 2; ++sn) {
        int base = (bv[sn] * R) * HW + iv[sn];
#pragma unroll
        for (int sm = 0; sm < 4; ++sm) {
#pragma unroll
            for (int reg = 0; reg < 4; ++reg) {
                int r = wm + sm * 16 + q * 4 + reg;
                cam[base + r * HW] = acc[sm][sn][reg];
            }
        }
    }
}

// ---------------- stats: embedding (mean + bias) and ddof=1 std ------------
__global__ __launch_bounds__(256) void stats_k(
    const float* __restrict__ ws, const float* __restrict__ b0,
    const float* __restrict__ b1, const float* __restrict__ b2,
    float* __restrict__ out) {
    int gw = blockIdx.x * 4 + (threadIdx.x >> 6);  // wave id, < 24576
    int lane = threadIdx.x & 63;
    int lvl = gw >> 13, row = gw & 8191;           // row = b*128 + r
    const int HW = (lvl == 0) ? 784 : (lvl == 1) ? 196 : 49;
    const float* cam = ws + ((lvl == 0) ? CAM0_OFF : (lvl == 1) ? CAM1_OFF : CAM2_OFF)
                        + (long)row * HW;
    float s = 0.f, ss = 0.f;
    for (int j = lane; j < HW; j += 64) { float v = cam[j]; s += v; ss += v * v; }
#pragma unroll
    for (int o = 32; o; o >>= 1) { s += __shfl_xor(s, o); ss += __shfl_xor(ss, o); }
    if (lane == 0) {
        const float* bias = (lvl == 0) ? b0 : (lvl == 1) ? b1 : b2;
        float mean = s / (float)HW;
        out[lvl * 8192 + row] = mean + bias[row & 127];
        float var = fmaxf(ss - s * mean, 0.f) / (float)(HW - 1);
        out[24576 + lvl * 8192 + row] = sqrtf(var);
    }
}

// ---------------- 2x2 average pooling: cam0->pool0, cam1->pool1 ------------
__global__ void pool_k(float* __restrict__ ws) {
    int id = blockIdx.x * 256 + threadIdx.x;   // < 2007040 exact
    if (id < 1605632) {
        int ow = id % 14, t1 = id / 14; int oh = t1 % 14; int row = t1 / 14;
        const float* src = ws + CAM0_OFF + (long)row * 784;
        int i0 = oh * 56 + ow * 2;
        ws[POOL0_OFF + id] = (src[i0] + src[i0 + 1] + src[i0 + 28] + src[i0 + 29]) * 0.25f;
    } else {
        int id2 = id - 1605632;
        int ow = id2 % 7, t1 = id2 / 7; int oh = t1 % 7; int row = t1 / 7;
        const float* src = ws + CAM1_OFF + (long)row * 196;
        int i0 = oh * 28 + ow * 2;
        ws[POOL1_OFF + id2] = (src[i0] + src[i0 + 1] + src[i0 + 14] + src[i0 + 15]) * 0.25f;
    }
}

// ---------------- in-place L2 normalize rows (torch F.normalize, eps 1e-12) -
__global__ __launch_bounds__(256) void normscale_k(float* __restrict__ ws) {
    int gw = blockIdx.x * 4 + (threadIdx.x >> 6);  // < 32768
    int lane = threadIdx.x & 63;
    int op = gw >> 13, row = gw & 8191;
    float* p; int K;
    if (op == 0)      { p = ws + POOL0_OFF + (long)row * 196; K = 196; }
    else if (op == 1) { p = ws + CAM1_OFF + (long)row * 196; K = 196; }
    else if (op == 2) { p = ws + POOL1_OFF + (long)row * 49; K = 49; }
    else              { p = ws + CAM2_OFF + (long)row * 49; K = 49; }
    float ss = 0.f;
    for (int j = lane; j < K; j += 64) { float v = p[j]; ss += v * v; }
#pragma unroll
    for (int o = 32; o; o >>= 1) ss += __shfl_xor(ss, o);
    float inv = 1.0f / fmaxf(sqrtf(ss), 1e-12f);
    for (int j = lane; j < K; j += 64) p[j] *= inv;
}

// ---------------- link partials: per (link, b, m-quarter, n-half) ----------
__global__ __launch_bounds__(256) void link_k(const float* __restrict__ ws,
                                              float* __restrict__ part) {
    extern __shared__ float lds[];
    float* hiT = lds;             // [196][68]
    float* loT = lds + 196 * 68;  // [196][36]
    int bid = blockIdx.x, tid = threadIdx.x;
    int lk = bid >> 9, rem = bid & 511;
    int b = rem >> 3, mq = (rem >> 1) & 3, nh = rem & 1;
    const int K = lk ? 49 : 196;
    const float* lo = ws + (lk ? POOL1_OFF : POOL0_OFF) + (long)(b * 128 + mq * 32) * K;
    const float* hi = ws + (lk ? CAM2_OFF : CAM1_OFF) + (long)(b * 128 + nh * 64) * K;
    for (int idx = tid; idx < 64 * K; idx += 256) {
        int nr = idx / K, i = idx - nr * K;
        hiT[i * 68 + nr] = hi[idx];
    }
    for (int idx = tid; idx < 32 * K; idx += 256) {
        int mr = idx / K, i = idx - mr * K;
        loT[i * 36 + mr] = lo[idx];
    }
    __syncthreads();
    int tm = tid >> 5, tn = tid & 31;
    int m0 = tm * 4, n0 = tn * 2;
    float a0x = 0, a0y = 0, a1x = 0, a1y = 0, a2x = 0, a2y = 0, a3x = 0, a3y = 0;
    for (int i = 0; i < K; ++i) {
        float4 lv = *(const float4*)&loT[i * 36 + m0];
        float2 hv = *(const float2*)&hiT[i * 68 + n0];
        a0x += lv.x * hv.x; a0y += lv.x * hv.y;
        a1x += lv.y * hv.x; a1y += lv.y * hv.y;
        a2x += lv.z * hv.x; a2y += lv.z * hv.y;
        a3x += lv.w * hv.x; a3y += lv.w * hv.y;
    }
    float* dst = part + lk * 1048576 + b * 16384 + (mq * 32 + m0) * 128 + nh * 64 + n0;
    dst[0] = a0x; dst[1] = a0y;
    dst[128] = a1x; dst[129] = a1y;
    dst[256] = a2x; dst[257] = a2y;
    dst[384] = a3x; dst[385] = a3y;
}

// ---------------- reduce partials over b, scale by 1/B ---------------------
__global__ void linkred_k(const float* __restrict__ part, float* __restrict__ out) {
    int id = blockIdx.x * 256 + threadIdx.x;  // < 32768
    int lk = id >> 14, mn = id & 16383;
    const float* p = part + lk * 1048576 + mn;
    float s = 0.f;
#pragma unroll 8
    for (int b = 0; b < 64; ++b) s += p[b * 16384];
    out[49152 + lk * 16384 + mn] = s * (1.0f / 64.0f);
}

extern "C" void kernel_launch(void* const* d_in, const int* in_sizes, int n_in,
                              void* d_out, int out_size, void* d_ws, size_t ws_size,
                              hipStream_t stream) {
    const float* f0 = (const float*)d_in[0];
    const float* w0 = (const float*)d_in[1];
    const float* b0 = (const float*)d_in[2];
    const float* f1 = (const float*)d_in[3];
    const float* w1 = (const float*)d_in[4];
    const float* b1 = (const float*)d_in[5];
    const float* f2 = (const float*)d_in[6];
    const float* w2 = (const float*)d_in[7];
    const float* b2 = (const float*)d_in[8];
    float* ws = (float*)d_ws;
    float* out = (float*)d_out;
    bf16* wb = (bf16*)(ws + WB_OFF);

    prep_w<<<1792, 256, 0, stream>>>(w0, w1, w2, wb);
    cam_gemm<<<1029, 256, 0, stream>>>(f0, f1, f2, wb, ws);
    stats_k<<<6144, 256, 0, stream>>>(ws, b0, b1, b2, out);
    pool_k<<<7840, 256, 0, stream>>>(ws);
    normscale_k<<<8192, 256, 0, stream>>>(ws);
    link_k<<<1024, 256, 81536, stream>>>(ws, ws + PART_OFF);
    linkred_k<<<128, 256, 0, stream>>>(ws + PART_OFF, out);
}